// Round 7
// baseline (439.229 us; speedup 1.0000x reference)
//
#include <hip/hip_runtime.h>
#include <hip/hip_bf16.h>

typedef __bf16 bf16x8 __attribute__((ext_vector_type(8)));
typedef __bf16 bf16x4 __attribute__((ext_vector_type(4)));
typedef float f32x4 __attribute__((ext_vector_type(4)));

#define ROWSG 32768          // B*T
#define RB 8                 // bt rows per block
#define HPAD 72              // bf16 row stride
#define NN_OFF ((size_t)ROWSG)
#define EYE_OFF ((size_t)ROWSG + (size_t)ROWSG*64)

// weight-cache offsets (bf16 elements), all WT[n][k] row-major, stride = Kp
#define OFF_EW1   0          // 64 x 224 (K=200 zero-padded)
#define OFF_EW2   14336      // 64 x 64
#define OFF_WQ    18432      // (unused by main now; kept for layout stability)
#define OFF_WK    22528      // (unused by main now)
#define OFF_WV    26624
#define OFF_WO    30720
#define OFF_F1    34816
#define OFF_F2    38912
#define OFF_W1A   43008      // 64 x 128
#define OFF_W1B   51200      // 256 x 64
#define OFF_HB1W  67584      // 32 x 128
#define OFF_W2A   71680      // 64 x 128
#define OFF_W2B   79872      // 32 x 64
#define OFF_HB2W1 81920      // 32 x 128
#define WS_TOTAL  86016
#define OFF_M     86016      // 64 x 64 : M'[f][e] = (Wq Wk^T)[e][f] / 8
#define WS_TOTAL2 90112

__device__ __align__(16) __bf16 g_ws[WS_TOTAL2];
__device__ float g_v[64];    // v[e] = (Wk bq)[e] / 8

#define MFMA16(a,b,c) __builtin_amdgcn_mfma_f32_16x16x32_bf16(a,b,c,0,0,0)

// ---------------- weight transform kernel ----------------
struct TP { const float* src[14]; };

__global__ __launch_bounds__(256) void wtrans(TP tp) {
    const int gid = blockIdx.x * 256 + threadIdx.x;
    if (gid >= WS_TOTAL) return;
    const int OFFS[14] = {OFF_EW1, OFF_EW2, OFF_WQ, OFF_WK, OFF_WV, OFF_WO, OFF_F1,
                          OFF_F2, OFF_W1A, OFF_W1B, OFF_HB1W, OFF_W2A, OFF_W2B, OFF_HB2W1};
    const int KPS[14]  = {224, 64, 64, 64, 64, 64, 64, 64, 128, 64, 128, 128, 64, 128};
    const int KRS[14]  = {200, 64, 64, 64, 64, 64, 64, 64, 128, 64, 128, 128, 64, 128};
    const int NS[14]   = {64, 64, 64, 64, 64, 64, 64, 64, 64, 256, 32, 64, 32, 32};
    int m = 0;
#pragma unroll
    for (int i = 1; i < 14; ++i) if (gid >= OFFS[i]) m = i;
    const int loc = gid - OFFS[m];
    const int Kp = KPS[m];
    const int n = loc / Kp;
    const int k = loc - n * Kp;
    float v = 0.f;
    if (k < KRS[m]) v = tp.src[m][(size_t)k * NS[m] + n];   // src is W[k][n]
    g_ws[gid] = (__bf16)v;
}

// ---------------- QK-fold precompute: M' and v ----------------
struct PP { const float *wq, *wk, *bq; };

__global__ __launch_bounds__(256) void wprep(PP pp) {
    const int t = threadIdx.x;
#pragma unroll 1
    for (int q = 0; q < 16; ++q) {
        const int idx = q * 256 + t;           // 4096 entries
        const int f = idx >> 6, e = idx & 63;
        float s = 0.f;
        for (int n = 0; n < 64; ++n) s += pp.wq[e * 64 + n] * pp.wk[f * 64 + n];
        g_ws[OFF_M + f * 64 + e] = (__bf16)(s * 0.125f);
    }
    if (t < 64) {
        float s = 0.f;
        for (int n = 0; n < 64; ++n) s += pp.wk[t * 64 + n] * pp.bq[n];
        g_v[t] = s * 0.125f;
    }
}

// ---------------- main fused kernel ----------------
struct MainP {
    const float *qvals, *states, *hid, *eb1, *eb2, *bq, *bk, *bv, *bo,
        *l1g, *l1b, *fb1, *fb2, *l2g, *l2b, *niw, *nib, *ng, *nb,
        *b1a, *b1b, *hb1b, *b2a, *b2b, *hb2b1, *hw2, *hb2b2;
    float* out;
};

// single-tile projection + bias + residual + LayerNorm (tile-local, barrier-free)
__device__ __forceinline__ void proj_ln_tile(const __bf16* A, const __bf16* WT,
                                             const float* bias, const float* g, const float* bb,
                                             __bf16* H, int mt, int quad, int l15) {
    f32x4 acc0 = {0,0,0,0}, acc1 = {0,0,0,0}, acc2 = {0,0,0,0}, acc3 = {0,0,0,0};
#pragma unroll
    for (int ks = 0; ks < 2; ++ks) {
        const int kk = ks * 32 + quad * 8;
        const bf16x8 af = *(const bf16x8*)(A + (mt * 16 + l15) * HPAD + kk);
        acc0 = MFMA16(af, *(const bf16x8*)(WT + (size_t)(0 * 16 + l15) * 64 + kk), acc0);
        acc1 = MFMA16(af, *(const bf16x8*)(WT + (size_t)(1 * 16 + l15) * 64 + kk), acc1);
        acc2 = MFMA16(af, *(const bf16x8*)(WT + (size_t)(2 * 16 + l15) * 64 + kk), acc2);
        acc3 = MFMA16(af, *(const bf16x8*)(WT + (size_t)(3 * 16 + l15) * 64 + kk), acc3);
    }
    float v[4][4], g4[4], b4[4];
#pragma unroll
    for (int nt = 0; nt < 4; ++nt) {
        const int col = nt * 16 + l15;
        const float bo = bias[col];
        g4[nt] = g[col]; b4[nt] = bb[col];
        const f32x4 a = (nt == 0) ? acc0 : (nt == 1) ? acc1 : (nt == 2) ? acc2 : acc3;
#pragma unroll
        for (int r = 0; r < 4; ++r)
            v[nt][r] = a[r] + bo + (float)H[(mt * 16 + quad * 4 + r) * HPAD + col];
    }
#pragma unroll
    for (int r = 0; r < 4; ++r) {
        float s  = v[0][r] + v[1][r] + v[2][r] + v[3][r];
        float s2 = v[0][r]*v[0][r] + v[1][r]*v[1][r] + v[2][r]*v[2][r] + v[3][r]*v[3][r];
#pragma unroll
        for (int off = 1; off < 16; off <<= 1) {
            s  += __shfl_xor(s,  off, 64);
            s2 += __shfl_xor(s2, off, 64);
        }
        const float mu  = s * 0.015625f;
        const float var = s2 * 0.015625f - mu * mu;
        const float rs  = rsqrtf(var + 1e-5f);
#pragma unroll
        for (int nt = 0; nt < 4; ++nt)
            H[(mt * 16 + quad * 4 + r) * HPAD + nt * 16 + l15] =
                (__bf16)((v[nt][r] - mu) * rs * g4[nt] + b4[nt]);
    }
}

// generic tile projection A(tile rows)@WT -> D(tile rows), in C-layout, with bias+act
template<int ACT>  // 0: none, 1: relu
__device__ __forceinline__ void proj_tile(const __bf16* A, const __bf16* WT, const float* bias,
                                          __bf16* D, int mt, int quad, int l15) {
    const int base = (mt * 16 + l15) * HPAD;
    const bf16x8 a0 = *(const bf16x8*)(A + base + quad * 8);
    const bf16x8 a1 = *(const bf16x8*)(A + base + 32 + quad * 8);
    f32x4 acc[4] = {{0,0,0,0},{0,0,0,0},{0,0,0,0},{0,0,0,0}};
#pragma unroll
    for (int nt = 0; nt < 4; ++nt) {
        acc[nt] = MFMA16(a0, *(const bf16x8*)(WT + (size_t)(nt * 16 + l15) * 64 + quad * 8), acc[nt]);
        acc[nt] = MFMA16(a1, *(const bf16x8*)(WT + (size_t)(nt * 16 + l15) * 64 + 32 + quad * 8), acc[nt]);
    }
#pragma unroll
    for (int nt = 0; nt < 4; ++nt) {
        const float bv = bias[nt * 16 + l15];
#pragma unroll
        for (int r = 0; r < 4; ++r) {
            float val = acc[nt][r] + bv;
            if (ACT == 1) val = fmaxf(val, 0.f);
            D[(mt * 16 + quad * 4 + r) * HPAD + nt * 16 + l15] = (__bf16)val;
        }
    }
}

__global__ __launch_bounds__(256) void mixer_main(MainP p) {
    __shared__ __align__(16) __bf16 Hb[80 * HPAD];   // h -> h2 -> h3
    __shared__ __align__(16) __bf16 Qb[80 * HPAD];   // G -> ah -> attv -> ffn hidden
    __shared__ __align__(16) __bf16 EbU[16 * HPAD];  // e -> Tb1
    __shared__ __align__(16) __bf16 Tb2[16 * HPAD];
    __shared__ __align__(16) __bf16 ensB[16 * 136];
    __shared__ __align__(16) char   uniB[3072];      // attU (P45) | B1f,W2f,T3f (P10s2+)
    __shared__ float sQv[64];
    __shared__ float qniL[64];
    __shared__ float vhS[80];
    __shared__ __align__(16) __bf16 W1bS[8 * 256];   // Sb (P0/P1) | sNi f32 (Y,X) | w1 (P10s2+)
    // static LDS = 40,000 B -> 3-4 blocks/CU

    float* attU = (float*)uniB;
    float* B1f  = (float*)uniB;
    float* W2f  = (float*)(uniB + 1024);
    float* T3f  = (float*)(uniB + 2048);
    float* sNi  = (float*)W1bS;
    __bf16* Sb  = W1bS;

    const int blk = blockIdx.x;
    const int bt0 = blk * RB;
    const int t = threadIdx.x;
    const int w = t >> 6, lane = t & 63, quad = lane >> 4, l15 = lane & 15;
    const __bf16* ws = g_ws;

    // ---- P0: stage hidden_state -> Hb; states -> Sb; qvals ----
#pragma unroll
    for (int it = 0; it < 4; ++it) {
        const int u = it * 256 + t;               // 1024 float4 units = RB*512 floats exactly
        const int x = u >> 7, rem = u & 127, n = rem >> 4, d4 = (rem & 15) * 4;
        const float4 v4 = *(const float4*)(p.hid + ((size_t)(bt0 + x) * 512 + n * 64 + d4));
        bf16x4 o; o[0] = (__bf16)v4.x; o[1] = (__bf16)v4.y; o[2] = (__bf16)v4.z; o[3] = (__bf16)v4.w;
        *(bf16x4*)(Hb + (x * 9 + n) * HPAD + d4) = o;
    }
#pragma unroll
    for (int it = 0; it < 2; ++it) {
        const int u = it * 256 + t;               // 400 float4 units = 8 rows x 200 floats
        if (u < 400) {
            const int xr = u / 50, c4 = u - xr * 50;
            const float4 v4 = *(const float4*)(p.states + (size_t)(bt0 + xr) * 200 + c4 * 4);
            bf16x4 o; o[0] = (__bf16)v4.x; o[1] = (__bf16)v4.y; o[2] = (__bf16)v4.z; o[3] = (__bf16)v4.w;
            *(bf16x4*)(Sb + xr * 224 + c4 * 4) = o;
        }
    }
    if (t < 192) { const int xr = t / 24, c = t - xr * 24; Sb[xr * 224 + 200 + c] = (__bf16)0.0f; }
    if (t < 64) sQv[t] = p.qvals[(size_t)(bt0 + (t >> 3)) * 8 + (t & 7)];
    __syncthreads();

    // ---- P1: encoder layer 1 (rows 8..15 dup row 7) ----
    float e4[4];
    {
        const int n0 = w * 16;
        const int srow = (l15 < 8) ? l15 : 7;
        f32x4 acc = {0, 0, 0, 0};
        for (int ks = 0; ks < 7; ++ks) {
            const int kk = ks * 32 + quad * 8;
            const bf16x8 af = *(const bf16x8*)(Sb + srow * 224 + kk);
            const bf16x8 bf = *(const bf16x8*)(ws + OFF_EW1 + (size_t)(n0 + l15) * 224 + kk);
            acc = MFMA16(af, bf, acc);
        }
        const float b1 = p.eb1[n0 + l15];
#pragma unroll
        for (int r = 0; r < 4; ++r) {
            const float ev = fmaxf(acc[r] + b1, 0.f);
            e4[r] = ev;
            EbU[(quad * 4 + r) * HPAD + n0 + l15] = (__bf16)ev;
        }
    }
    __syncthreads();

    // ---- P2: enc = tanh(e@W2 + e + b2) -> Hb row x*9+8, ensB[:,0:64] ----
    {
        const int n0 = w * 16;
        f32x4 acc = {0, 0, 0, 0};
#pragma unroll
        for (int ks = 0; ks < 2; ++ks) {
            const int kk = ks * 32 + quad * 8;
            const bf16x8 af = *(const bf16x8*)(EbU + l15 * HPAD + kk);
            const bf16x8 bf = *(const bf16x8*)(ws + OFF_EW2 + (size_t)(n0 + l15) * 64 + kk);
            acc = MFMA16(af, bf, acc);
        }
        const float b2 = p.eb2[n0 + l15];
#pragma unroll
        for (int r = 0; r < 4; ++r) {
            const int xr = quad * 4 + r;
            if (xr < RB) {
                const float ev = tanhf(acc[r] + e4[r] + b2);
                Hb[(xr * 9 + 8) * HPAD + n0 + l15] = (__bf16)ev;
                ensB[xr * 136 + n0 + l15] = (__bf16)ev;
            }
        }
    }
    __syncthreads();

    // ---- P3: G = h @ M' (20 tile-jobs, 5/wave); vh_j = h_j . v ----
    for (int it = 0; it < 5; ++it) {
        const int j = w + 4 * it;                 // 0..19
        const int mt = j >> 2, nt = j & 3;
        f32x4 acc = {0, 0, 0, 0};
#pragma unroll
        for (int ks = 0; ks < 2; ++ks) {
            const int kk = ks * 32 + quad * 8;
            const bf16x8 af = *(const bf16x8*)(Hb + (mt * 16 + l15) * HPAD + kk);
            const bf16x8 bf = *(const bf16x8*)(ws + OFF_M + (size_t)(nt * 16 + l15) * 64 + kk);
            acc = MFMA16(af, bf, acc);
        }
#pragma unroll
        for (int r = 0; r < 4; ++r)
            Qb[(mt * 16 + quad * 4 + r) * HPAD + nt * 16 + l15] = (__bf16)acc[r];
    }
    if (t < 72) {
        float s = 0.f;
#pragma unroll
        for (int c8 = 0; c8 < 8; ++c8) {
            const bf16x8 hv = *(const bf16x8*)(Hb + t * HPAD + c8 * 8);
#pragma unroll
            for (int jj = 0; jj < 8; ++jj) s += (float)hv[jj] * g_v[c8 * 8 + jj];
        }
        vhS[t] = s;
    }
    __syncthreads();

    // ---- P45: S = G h^T + vh_j -> softmax -> attU; ah = att @ h -> Qb (wave owns x) ----
    for (int xi = 0; xi < 2; ++xi) {
        const int x = w * 2 + xi;
        const int arow = (x * 9 + l15) * HPAD;    // rows i>=9 garbage -> discarded C rows
        f32x4 acc = {0, 0, 0, 0};
#pragma unroll
        for (int ks = 0; ks < 2; ++ks) {
            const int kk = ks * 32 + quad * 8;
            acc = MFMA16(*(const bf16x8*)(Qb + arow + kk), *(const bf16x8*)(Hb + arow + kk), acc);
        }
        const float vh = (l15 < 9) ? vhS[x * 9 + l15] : 0.f;
#pragma unroll
        for (int r = 0; r < 4; ++r) {
            const int i = quad * 4 + r;
            float s = (l15 < 9) ? (acc[r] + vh) : -3.0e38f;
            float m = s;
#pragma unroll
            for (int off = 1; off < 16; off <<= 1) m = fmaxf(m, __shfl_xor(m, off, 64));
            float e = (l15 < 9) ? __expf(s - m) : 0.f;
            float sum = e;
#pragma unroll
            for (int off = 1; off < 16; off <<= 1) sum += __shfl_xor(sum, off, 64);
            if (i < 9 && l15 < 9) attU[x * 81 + i * 9 + l15] = e / sum;
        }
        // ah for same x (same wave; LDS in-order guarantees RAW on attU)
        float vreg[9];
#pragma unroll
        for (int jj = 0; jj < 9; ++jj) vreg[jj] = (float)Hb[(x * 9 + jj) * HPAD + lane];
#pragma unroll
        for (int i = 0; i < 9; ++i) {
            float a = 0.f;
#pragma unroll
            for (int jj = 0; jj < 9; ++jj) a += attU[x * 81 + i * 9 + jj] * vreg[jj];
            Qb[(x * 9 + i) * HPAD + lane] = (__bf16)a;
        }
    }
    __syncthreads();

    // ---- P6 mega-phase (tile-local, barrier-free): attv -> LN1 -> FFN1 -> LN2 ----
    for (int mti = 0; mti < 2; ++mti) {
        const int mt = w + 4 * mti;
        if (mt >= 5) continue;
        proj_tile<0>(Qb, ws + OFF_WV, p.bv, Qb, mt, quad, l15);           // attv = ah@Wv+bv (in-place)
        proj_ln_tile(Qb, ws + OFF_WO, p.bo, p.l1g, p.l1b, Hb, mt, quad, l15); // h2
        proj_tile<1>(Hb, ws + OFF_F1, p.fb1, Qb, mt, quad, l15);          // f = relu(h2@F1+b)
        proj_ln_tile(Qb, ws + OFF_F2, p.fb2, p.l2g, p.l2b, Hb, mt, quad, l15); // h3
    }
    __syncthreads();

    // ---- Y: ens second half (mean of h3 heads) + ni sigmoid-LN -> sNi ----
#pragma unroll
    for (int it = 0; it < 2; ++it) {
        const int id = it * 256 + t;
        const int x = id >> 6, col = id & 63;
        float s = 0.f;
#pragma unroll
        for (int i = 0; i < 8; ++i) s += (float)Hb[(x * 9 + i) * HPAD + col];
        ensB[x * 136 + 64 + col] = (__bf16)(s * 0.125f);
    }
    {
        const int pr = t >> 2, q4 = t & 3;
        const int x = pr >> 3, n = pr & 7;
        float acc[7] = {0.f, 0.f, 0.f, 0.f, 0.f, 0.f, 0.f};
        const float* wni = p.niw + n * 448;
        for (int dd = 0; dd < 16; ++dd) {
            const int d = q4 * 16 + dd;
            const float hv = (float)Hb[(x * 9 + n) * HPAD + d];
#pragma unroll
            for (int e = 0; e < 7; ++e) acc[e] += hv * wni[d * 7 + e];
        }
#pragma unroll
        for (int e = 0; e < 7; ++e) {
            acc[e] += __shfl_xor(acc[e], 1, 64);
            acc[e] += __shfl_xor(acc[e], 2, 64);
        }
        if (q4 == 0) {
            float s = 0.f;
#pragma unroll
            for (int e = 0; e < 7; ++e) { acc[e] += p.nib[n * 7 + e]; s += acc[e]; }
            const float mu = s * (1.f / 7.f);
            float s2 = 0.f;
#pragma unroll
            for (int e = 0; e < 7; ++e) { const float d0 = acc[e] - mu; s2 += d0 * d0; }
            const float rs = rsqrtf(s2 * (1.f / 7.f) + 1e-5f);
#pragma unroll
            for (int e = 0; e < 7; ++e) {
                const float vv = (acc[e] - mu) * rs * p.ng[e] + p.nb[e];
                sNi[x * 64 + n * 8 + e] = 1.f / (1.f + __expf(-vv));
            }
        }
    }
    __syncthreads();

    // ---- X: N_nn/eye outputs + q_ni (both straight from sNi) + hyper stage-1 ----
#pragma unroll
    for (int it = 0; it < 2; ++it) {
        const int id = it * 256 + t;
        const int x = id >> 6, rem = id & 63, i = rem >> 3, jj = rem & 7;
        const float nf = (i == jj) ? 1.f : sNi[x * 64 + i * 8 + (jj - (jj > i ? 1 : 0))];
        p.out[NN_OFF + (size_t)(bt0 + x) * 64 + rem] = nf;
        p.out[EYE_OFF + (size_t)(bt0 + x) * 64 + rem] = (i == jj) ? 1.f : 0.f;
    }
    {
        const int pr = t >> 2, q4 = t & 3;
        const int x = pr >> 3, i = pr & 7;
        float s = 0.f;
#pragma unroll
        for (int jo = 0; jo < 2; ++jo) {
            const int j = q4 * 2 + jo;
            const float nf = (j == i) ? 1.f : sNi[x * 64 + i * 8 + (j - (j > i ? 1 : 0))];
            s += sQv[x * 8 + j] * nf;
        }
        s += __shfl_xor(s, 1, 64);
        s += __shfl_xor(s, 2, 64);
        if (q4 == 0) qniL[x * 8 + i] = s;
    }
    {
        const int n0 = w * 16;
#pragma unroll
        for (int m2 = 0; m2 < 2; ++m2) {
            const __bf16* wt = ws + (m2 == 0 ? OFF_W1A : OFF_W2A);
            const float* bias = m2 == 0 ? p.b1a : p.b2a;
            __bf16* dst = m2 == 0 ? EbU : Tb2;
            f32x4 acc = {0, 0, 0, 0};
#pragma unroll
            for (int ks = 0; ks < 4; ++ks) {
                const int kk = ks * 32 + quad * 8;
                const bf16x8 af = *(const bf16x8*)(ensB + l15 * 136 + kk);
                const bf16x8 bf = *(const bf16x8*)(wt + (size_t)(n0 + l15) * 128 + kk);
                acc = MFMA16(af, bf, acc);
            }
            const float bb = bias[n0 + l15];
#pragma unroll
            for (int r = 0; r < 4; ++r)
                dst[(quad * 4 + r) * HPAD + n0 + l15] = (__bf16)fmaxf(acc[r] + bb, 0.f);
        }
    }
    __syncthreads();

    // ---- P10s2: w1 (16), b1 (2), w2 (2), t3 (2) = 22 tile-jobs ----
    for (int it = 0; it < 6; ++it) {
        const int j = w + 4 * it;
        if (j >= 22) continue;
        int mode, n0, Kp, ksteps, aStride;
        const __bf16 *A, *WT; const float* bias;
        if (j < 16)      { mode = 0; n0 = j * 16;        A = EbU;  aStride = HPAD; WT = ws + OFF_W1B;   bias = p.b1b;  Kp = 64;  ksteps = 2; }
        else if (j < 18) { mode = 1; n0 = (j - 16) * 16; A = ensB; aStride = 136;  WT = ws + OFF_HB1W;  bias = p.hb1b; Kp = 128; ksteps = 4; }
        else if (j < 20) { mode = 2; n0 = (j - 18) * 16; A = Tb2;  aStride = HPAD; WT = ws + OFF_W2B;   bias = p.b2b;  Kp = 64;  ksteps = 2; }
        else             { mode = 3; n0 = (j - 20) * 16; A = ensB; aStride = 136;  WT = ws + OFF_HB2W1; bias = p.hb2b1;Kp = 128; ksteps = 4; }
        f32x4 acc = {0, 0, 0, 0};
        for (int ks = 0; ks < ksteps; ++ks) {
            const int kk = ks * 32 + quad * 8;
            const bf16x8 af = *(const bf16x8*)(A + l15 * aStride + kk);
            const bf16x8 bf = *(const bf16x8*)(WT + (size_t)(n0 + l15) * Kp + kk);
            acc = MFMA16(af, bf, acc);
        }
        const float bb = bias[n0 + l15];
#pragma unroll
        for (int r = 0; r < 4; ++r) {
            const int xr = quad * 4 + r;
            if (xr < RB) {
                const float val = acc[r] + bb;
                if (mode == 0)      W1bS[xr * 256 + n0 + l15] = (__bf16)fabsf(val);
                else if (mode == 1) B1f[xr * 32 + n0 + l15] = val;
                else if (mode == 2) W2f[xr * 32 + n0 + l15] = fabsf(val);
                else                T3f[xr * 32 + n0 + l15] = fmaxf(val, 0.f);
            }
        }
    }
    __syncthreads();

    // ---- P11: hidden = elu(q_ni@w1 + b1); y = hidden@w2 + b2 ----
    if (t < 128) {
        const int x = t >> 4, sub = t & 15;
        float pp = 0.f, pb = 0.f;
#pragma unroll
        for (int h2i = 0; h2i < 2; ++h2i) {
            const int e = sub + h2i * 16;
            float a = B1f[x * 32 + e];
#pragma unroll
            for (int i = 0; i < 8; ++i) a += qniL[x * 8 + i] * (float)W1bS[x * 256 + i * 32 + e];
            const float hid = a > 0.f ? a : (__expf(a) - 1.f);
            pp += hid * W2f[x * 32 + e];
            pb += T3f[x * 32 + e] * p.hw2[e];
        }
#pragma unroll
        for (int off = 1; off < 16; off <<= 1) {
            pp += __shfl_xor(pp, off, 64);
            pb += __shfl_xor(pb, off, 64);
        }
        if (sub == 0) p.out[bt0 + x] = pp + pb + p.hb2b2[0];
    }
}

extern "C" void kernel_launch(void* const* d_in, const int* in_sizes, int n_in,
                              void* d_out, int out_size, void* d_ws, size_t ws_size,
                              hipStream_t stream) {
    TP tp;
    tp.src[0]  = (const float*)d_in[3];   // enc_w1
    tp.src[1]  = (const float*)d_in[5];   // enc_w2
    tp.src[2]  = (const float*)d_in[7];   // wq
    tp.src[3]  = (const float*)d_in[9];   // wk
    tp.src[4]  = (const float*)d_in[11];  // wv
    tp.src[5]  = (const float*)d_in[13];  // wo
    tp.src[6]  = (const float*)d_in[17];  // ffn_w1
    tp.src[7]  = (const float*)d_in[19];  // ffn_w2
    tp.src[8]  = (const float*)d_in[27];  // w1a
    tp.src[9]  = (const float*)d_in[29];  // w1b
    tp.src[10] = (const float*)d_in[31];  // hb1w
    tp.src[11] = (const float*)d_in[33];  // w2a
    tp.src[12] = (const float*)d_in[35];  // w2b
    tp.src[13] = (const float*)d_in[37];  // hb2w1
    wtrans<<<(WS_TOTAL + 255) / 256, 256, 0, stream>>>(tp);

    PP pqk;
    pqk.wq = (const float*)d_in[7];
    pqk.wk = (const float*)d_in[9];
    pqk.bq = (const float*)d_in[8];
    wprep<<<1, 256, 0, stream>>>(pqk);

    MainP p;
    p.qvals = (const float*)d_in[0];
    p.states = (const float*)d_in[1];
    p.hid = (const float*)d_in[2];
    p.eb1 = (const float*)d_in[4];
    p.eb2 = (const float*)d_in[6];
    p.bq = (const float*)d_in[8];
    p.bk = (const float*)d_in[10];
    p.bv = (const float*)d_in[12];
    p.bo = (const float*)d_in[14];
    p.l1g = (const float*)d_in[15];
    p.l1b = (const float*)d_in[16];
    p.fb1 = (const float*)d_in[18];
    p.fb2 = (const float*)d_in[20];
    p.l2g = (const float*)d_in[21];
    p.l2b = (const float*)d_in[22];
    p.niw = (const float*)d_in[23];
    p.nib = (const float*)d_in[24];
    p.ng = (const float*)d_in[25];
    p.nb = (const float*)d_in[26];
    p.b1a = (const float*)d_in[28];
    p.b1b = (const float*)d_in[30];
    p.hb1b = (const float*)d_in[32];
    p.b2a = (const float*)d_in[34];
    p.b2b = (const float*)d_in[36];
    p.hb2b1 = (const float*)d_in[38];
    p.hw2 = (const float*)d_in[39];
    p.hb2b2 = (const float*)d_in[40];
    p.out = (float*)d_out;

    mixer_main<<<ROWSG / RB, 256, 0, stream>>>(p);
}